// Round 15
// baseline (1329.675 us; speedup 1.0000x reference)
//
#include <hip/hip_runtime.h>

#define DEV __device__ __forceinline__

typedef __bf16 bf16;
typedef __bf16 bf16x4 __attribute__((ext_vector_type(4)));
typedef __bf16 bf16x8 __attribute__((ext_vector_type(8)));
typedef float f32x4 __attribute__((ext_vector_type(4)));

constexpr int B_ = 4, S_ = 1024, D_ = 1024, H_ = 16, F_ = 4096, L_ = 4, SPAN_ = 512, DH_ = 64;
constexpr float SCALE_ = 0.07216878364870322f;  // 1/sqrt(3*DH)
constexpr float LOG2E_ = 1.4426950408889634f;
constexpr float SCL2_ = SCALE_ * LOG2E_;
constexpr float THR2_ = 11.5f;  // defer-max threshold in log2 units (~8 nats)
constexpr long POSL_ = 32L * 1024 * 64;  // pospk elements per layer

DEV void gload_lds16(const void* g, void* l) {
  __builtin_amdgcn_global_load_lds((const __attribute__((address_space(1))) void*)g,
                                   (__attribute__((address_space(3))) void*)l, 16, 0, 0);
}

// DPP cross-lane within 16-lane rows (VALU, not LDS pipe)
template <int CTRL>
DEV float dppf(float x) {
  return __builtin_bit_cast(
      float, __builtin_amdgcn_mov_dpp(__builtin_bit_cast(int, x), CTRL, 0xf, 0xf, true));
}
DEV float rowMax16(float v) {
  v = fmaxf(v, dppf<0x128>(v));
  v = fmaxf(v, dppf<0x124>(v));
  v = fmaxf(v, dppf<0x122>(v));
  v = fmaxf(v, dppf<0x121>(v));
  return v;
}
DEV float rowSum16(float v) {
  v += dppf<0x128>(v);
  v += dppf<0x124>(v);
  v += dppf<0x122>(v);
  v += dppf<0x121>(v);
  return v;
}

DEV float blockSum4(float v, volatile float* red) {
#pragma unroll
  for (int o = 32; o; o >>= 1) v += __shfl_xor(v, o);
  if ((threadIdx.x & 63) == 0) red[threadIdx.x >> 6] = v;
  __syncthreads();
  return red[0] + red[1] + red[2] + red[3];
}

// swizzled MFMA-fragment read from a [rows][64] bf16 LDS tile (128 B rows)
DEV bf16x8 lds_frag(const bf16* buf, int row, int chunk) {
  return *(const bf16x8*)((const char*)buf + row * 128 + ((chunk ^ (row & 7)) << 4));
}
DEV bf16x8 rdfrag(const char* base, int row, int chunk) {
  return *(const bf16x8*)(base + row * 128 + ((chunk ^ (row & 7)) << 4));
}

// ============ 256x256 deep-pipelined GEMM: C = A[M,K] @ B^T, BK=64 ==========
// EPI: 0 f32 | 3 bf16+bias | 4 bf16 gelu+bias
template <int EPI>
__global__ __launch_bounds__(512, 1) void gemm256(
    const bf16* __restrict__ A, const bf16* __restrict__ Bm,
    const float* __restrict__ bias, void* __restrict__ Cout,
    int K, int lda, int ldb, int ldc, long sA, long sB, long sC) {
  extern __shared__ __align__(16) char smem[];  // A dbuf [2][256][64] @0, B @65536

  const int z = blockIdx.z;
  A += (long)z * sA;
  Bm += (long)z * sB;
  const long coff = (long)z * sC;

  const int nwg = gridDim.x * gridDim.y;
  const int flat = blockIdx.y * gridDim.x + blockIdx.x;
  const int qq = nwg >> 3;
  const int swz = (flat & 7) * qq + (flat >> 3);
  const int bx = swz % gridDim.x, by = swz / gridDim.x;
  const int m0 = by * 256, n0 = bx * 256;

  const int tid = threadIdx.x, lane = tid & 63, wave = tid >> 6;
  const int wr = wave >> 2, wc = wave & 3;
  const int fr = lane & 15, fq = lane >> 4;

  f32x4 acc[8][4];
#pragma unroll
  for (int m = 0; m < 8; m++)
#pragma unroll
    for (int n = 0; n < 4; n++) acc[m][n] = f32x4{0.f, 0.f, 0.f, 0.f};

  const int r8 = tid >> 3;
  const int swzel = ((tid & 7) ^ (r8 & 7)) << 3;
  const bf16* ga = A + (long)(m0 + r8) * lda + swzel;
  const bf16* gb = Bm + (long)(n0 + r8) * ldb + swzel;

  const int NT = K >> 6;

  auto stage = [&](int t) {
    const long ko = (long)t * 64;
    char* da = smem + ((t & 1) << 15) + wave * 1024;
    gload_lds16(ga + ko, da);
    gload_lds16(ga + 64 * (long)lda + ko, da + 8192);
    gload_lds16(ga + 128 * (long)lda + ko, da + 16384);
    gload_lds16(ga + 192 * (long)lda + ko, da + 24576);
    char* db = smem + 65536 + ((t & 1) << 15) + wave * 1024;
    gload_lds16(gb + ko, db);
    gload_lds16(gb + 64 * (long)ldb + ko, db + 8192);
    gload_lds16(gb + 128 * (long)ldb + ko, db + 16384);
    gload_lds16(gb + 192 * (long)ldb + ko, db + 24576);
  };

  stage(0);
  asm volatile("s_waitcnt vmcnt(0)" ::: "memory");
  __builtin_amdgcn_s_barrier();

  for (int j = 0; j < NT; j++) {
    const char* Ac = smem + ((j & 1) << 15);
    const char* Bc = smem + 65536 + ((j & 1) << 15);

    if (j + 1 < NT) stage(j + 1);

    bf16x8 af[4][2], bfg[4][2];
#pragma unroll
    for (int m = 0; m < 4; m++) {
      const int ar = wr * 128 + m * 16 + fr;
      af[m][0] = rdfrag(Ac, ar, fq);
      af[m][1] = rdfrag(Ac, ar, 4 + fq);
    }
#pragma unroll
    for (int n = 0; n < 4; n++) {
      const int br = wc * 64 + n * 16 + fr;
      bfg[n][0] = rdfrag(Bc, br, fq);
      bfg[n][1] = rdfrag(Bc, br, 4 + fq);
    }

    __builtin_amdgcn_s_setprio(1);
#pragma unroll
    for (int m = 0; m < 4; m++)
#pragma unroll
      for (int n = 0; n < 4; n++)
#pragma unroll
        for (int kc = 0; kc < 2; kc++)
          acc[m][n] = __builtin_amdgcn_mfma_f32_16x16x32_bf16(af[m][kc], bfg[n][kc],
                                                              acc[m][n], 0, 0, 0);
    __builtin_amdgcn_s_setprio(0);
    __builtin_amdgcn_sched_barrier(0);

#pragma unroll
    for (int m = 0; m < 4; m++) {
      const int ar = wr * 128 + (m + 4) * 16 + fr;
      af[m][0] = rdfrag(Ac, ar, fq);
      af[m][1] = rdfrag(Ac, ar, 4 + fq);
    }
    __builtin_amdgcn_s_setprio(1);
#pragma unroll
    for (int m = 0; m < 4; m++)
#pragma unroll
      for (int n = 0; n < 4; n++)
#pragma unroll
        for (int kc = 0; kc < 2; kc++)
          acc[m + 4][n] = __builtin_amdgcn_mfma_f32_16x16x32_bf16(af[m][kc], bfg[n][kc],
                                                                  acc[m + 4][n], 0, 0, 0);
    __builtin_amdgcn_s_setprio(0);

    asm volatile("s_waitcnt vmcnt(0)" ::: "memory");
    __builtin_amdgcn_s_barrier();
  }

#pragma unroll
  for (int m = 0; m < 8; m++) {
#pragma unroll
    for (int n = 0; n < 4; n++) {
      const int col = n0 + wc * 64 + n * 16 + fr;
      float bval = 0.f;
      if constexpr (EPI == 3 || EPI == 4) bval = bias ? bias[col] : 0.f;
#pragma unroll
      for (int rr = 0; rr < 4; rr++) {
        const int row = m0 + wr * 128 + m * 16 + fq * 4 + rr;
        const long idx = coff + (long)row * ldc + col;
        const float v = acc[m][n][rr];
        if constexpr (EPI == 0) ((float*)Cout)[idx] = v;
        else if constexpr (EPI == 3) ((bf16*)Cout)[idx] = (bf16)(v + bval);
        else if constexpr (EPI == 4) {
          float x = v + bval;
          x = 0.5f * x * (1.f + erff(x * 0.70710678118654752f));
          ((bf16*)Cout)[idx] = (bf16)x;
        }
      }
    }
  }
}

// --------- 128-tile GEMM (pos EPI=5; Wo split-K EPI=0; QKV EPI=3) -----------
template <int EPI>
__global__ __launch_bounds__(256) void gemm_bt(
    const bf16* __restrict__ A, const bf16* __restrict__ Bm,
    const float* __restrict__ bias, void* __restrict__ Cout,
    int M, int N, int K, int lda, int ldb, int ldc, float alpha,
    long sA, long sB, long sC, long sBias) {
  __shared__ alignas(16) bf16 As[128 * 64];
  __shared__ alignas(16) bf16 Bs[128 * 64];

  const int z = blockIdx.z;
  A += (long)z * sA;
  Bm += (long)z * sB;
  bias += (long)z * sBias;
  const long coff = (long)z * sC;

  const int nwg = gridDim.x * gridDim.y;
  const int flat = blockIdx.y * gridDim.x + blockIdx.x;
  const int qq = nwg >> 3;
  const int swz = (flat & 7) * qq + (flat >> 3);
  const int bx = swz % gridDim.x, by = swz / gridDim.x;

  const int m0 = by * 128, n0 = bx * 128;
  const int tid = threadIdx.x, lane = tid & 63, wave = tid >> 6;
  const int wr = wave >> 1, wc = wave & 1;
  const int fr = lane & 15, fq = lane >> 4;

  f32x4 acc[4][4];
#pragma unroll
  for (int m = 0; m < 4; m++)
#pragma unroll
    for (int n = 0; n < 4; n++) acc[m][n] = f32x4{0.f, 0.f, 0.f, 0.f};

  const int r8 = tid >> 3;
  const int swzel = ((tid & 7) ^ (r8 & 7)) << 3;
  const bf16* ga = A + (long)(m0 + r8) * lda + swzel;
  const bf16* gb = Bm + (long)(n0 + r8) * ldb + swzel;
  const int swzrd = fr & 7;

  for (int k0 = 0; k0 < K; k0 += 64) {
#pragma unroll
    for (int i = 0; i < 4; i++)
      gload_lds16(ga + (long)i * 32 * lda + k0, (char*)As + i * 4096 + wave * 1024);
#pragma unroll
    for (int i = 0; i < 4; i++)
      gload_lds16(gb + (long)i * 32 * ldb + k0, (char*)Bs + i * 4096 + wave * 1024);
    __syncthreads();
#pragma unroll
    for (int kc = 0; kc < 2; kc++) {
      bf16x8 af[4], bfv[4];
#pragma unroll
      for (int m = 0; m < 4; m++)
        af[m] = *(const bf16x8*)((char*)As + (wr * 64 + m * 16 + fr) * 128 +
                                 (((kc * 4 + fq) ^ swzrd) << 4));
#pragma unroll
      for (int n = 0; n < 4; n++)
        bfv[n] = *(const bf16x8*)((char*)Bs + (wc * 64 + n * 16 + fr) * 128 +
                                  (((kc * 4 + fq) ^ swzrd) << 4));
#pragma unroll
      for (int m = 0; m < 4; m++)
#pragma unroll
        for (int n = 0; n < 4; n++)
          acc[m][n] = __builtin_amdgcn_mfma_f32_16x16x32_bf16(af[m], bfv[n], acc[m][n], 0, 0, 0);
    }
    __syncthreads();
  }

#pragma unroll
  for (int m = 0; m < 4; m++) {
#pragma unroll
    for (int n = 0; n < 4; n++) {
      const int col = n0 + wc * 64 + n * 16 + fr;
      float bval = 0.f;
      if constexpr (EPI == 3 || EPI == 4 || EPI == 5) bval = bias ? bias[col] : 0.f;
#pragma unroll
      for (int rr = 0; rr < 4; rr++) {
        const int row = m0 + wr * 64 + m * 16 + fq * 4 + rr;
        const long idx = coff + (long)row * ldc + col;
        const float v = acc[m][n][rr];
        if constexpr (EPI == 0) ((float*)Cout)[idx] = v * alpha;
        else if constexpr (EPI == 3) ((bf16*)Cout)[idx] = (bf16)(v + bval);
        else if constexpr (EPI == 4) {
          float x = v + bval;
          x = 0.5f * x * (1.f + erff(x * 0.70710678118654752f));
          ((bf16*)Cout)[idx] = (bf16)x;
        } else if constexpr (EPI == 5) {
          const long pidx = coff + ((long)(col >> 6) * 1024 + row) * 64 + (col & 63);
          ((bf16*)Cout)[pidx] = (bf16)(v + bval);
        }
      }
    }
  }
}

// ---- repack: k-section of qkv -> kp[bh][s][64]; v-section -> vp[bh][kt][dh][64]
__global__ __launch_bounds__(256) void repack_kv(const bf16* __restrict__ qkv,
                                                 bf16* __restrict__ kp,
                                                 bf16* __restrict__ vp) {
  const int kt = blockIdx.x, bh = blockIdx.y;
  const int b = bh >> 4, h = bh & 15;
  const int k0 = kt * 64;
  __shared__ bf16 t[64][72];
  const int ty = threadIdx.x >> 3, tx = threadIdx.x & 7;
#pragma unroll
  for (int p = 0; p < 2; p++) {
    const int s = k0 + p * 32 + ty;
    const long base = (long)(b * 1024 + s) * 3072 + h * 64;
    bf16x8 kv = *(const bf16x8*)(qkv + base + 1024 + tx * 8);
    *(bf16x8*)(kp + ((long)(bh * 1024 + s) << 6) + tx * 8) = kv;
    bf16x8 vv = *(const bf16x8*)(qkv + base + 2048 + tx * 8);
    *(bf16x8*)(&t[p * 32 + ty][tx * 8]) = vv;
  }
  __syncthreads();
  const int dh = threadIdx.x >> 2, sc = (threadIdx.x & 3) * 16;
  bf16 tmp[16];
#pragma unroll
  for (int j = 0; j < 16; j++) tmp[j] = t[sc + j][dh];
  bf16* dst = vp + ((long)(bh * 16 + kt) << 12) + dh * 64 + sc;
  *(bf16x8*)dst = *(bf16x8*)tmp;
  *(bf16x8*)(dst + 8) = *(bf16x8*)(tmp + 8);
}

// ============== fused attention: QK^T + rel-pos bias + softmax + PV =========
// 5-phase, 54272 B LDS (3 blocks/CU): A1{PXk,Ks,Vs} B1{c2p+S} A2{PXq} B2{p2c} D
__global__ __launch_bounds__(256) void attn_fused(
    const bf16* __restrict__ qkv, const bf16* __restrict__ kp,
    const bf16* __restrict__ vp, const bf16* __restrict__ pospk,
    const float* __restrict__ mask, bf16* __restrict__ ctx) {
  const int id = blockIdx.x;
  const int xcd = id & 7, sub = id >> 3;
  const int bh = xcd + 8 * (sub >> 4);
  const int qt = sub & 15;
  const int b = bh >> 4, h = bh & 15;
  const int q0 = qt * 64;
  const int tid = threadIdx.x, wave = tid >> 6, lane = tid & 63;
  const int fr = lane & 15, fq = lane >> 4;

  // LDS (54272 B, 3 blocks/CU):
  //  [0,16384)      PX [128][64] swz: PXk (A1-stage, B1-read) then PXq
  //                 (A2-stage, B2-read)  ∪  p_l [4][2048] (D)
  //  [16384,24576)  Ks  [64][64] swz  (A1-stage, B1-read)
  //  [24576,32768)  Vs  [64][64] swz  (A1-stage, D-read)
  //  [32768,45568)  c2p_T per-wave [80][20] (B1-write own, D-read own)
  //  [45568,54272)  p2c_P [64 ki][68]: toff = tp-ki in [0,64) (B2-write, D-read)
  __shared__ alignas(16) char smem[54272];
  bf16* PX = (bf16*)smem;
  char* p_l = smem;
  bf16* Ks = (bf16*)(smem + 16384);
  bf16* Vs = (bf16*)(smem + 24576);
  bf16* c2p_T = (bf16*)(smem + 32768);
  bf16* p2c_P = (bf16*)(smem + 45568);

  const bf16* posq = pospk + ((long)h << 16);
  const bf16* posk = pospk + ((long)(16 + h) << 16);
  const bf16* kbase = kp + ((long)bh << 16);
  const bf16* vbase = vp + ((long)bh << 16);

  bf16x8 qa[2];
  {
    const bf16* qrow = qkv + (long)(b * 1024 + q0 + wave * 16 + fr) * 3072 + h * 64;
    qa[0] = *(const bf16x8*)(qrow + fq * 8);
    qa[1] = *(const bf16x8*)(qrow + 32 + fq * 8);
  }

  f32x4 o[4];
#pragma unroll
  for (int n = 0; n < 4; n++) o[n] = f32x4{0.f, 0.f, 0.f, 0.f};
  float m_r[4], l_r[4];
#pragma unroll
  for (int r = 0; r < 4; r++) { m_r[r] = -1e30f; l_r[r] = 0.f; }

  char* pl_base = p_l + wave * 2048;
  bf16* c2p_w = c2p_T + wave * 1600;  // [80][20]
  const int wbyte = wave * 1024;

  for (int kt = 0; kt < 16; kt++) {
    const int k0 = kt * 64;

    // ---- phase A1: stage PXk window, K tile, V tile -------------------------
    __syncthreads();  // prior-iteration readers of Vs/c2p_T/p2c_P/p_l done
    {
      const int j0k = q0 - k0 + 449;
#pragma unroll
      for (int c = 0; c < 4; c++) {
        const int u = c * 256 + tid;
        const int rr = u >> 3;
        const int sel = (((u & 7) ^ (rr & 7)) << 3);
        int jk = j0k + rr;
        jk = jk < 0 ? 0 : (jk > 1023 ? 1023 : jk);
        gload_lds16(posk + ((long)jk << 6) + sel, (char*)PX + c * 4096 + wbyte);
      }
#pragma unroll
      for (int c = 0; c < 2; c++) {
        const int u = c * 256 + tid;
        const int rr = u >> 3;
        const int sel = (((u & 7) ^ (rr & 7)) << 3);
        gload_lds16(kbase + ((long)(k0 + rr) << 6) + sel, (char*)Ks + c * 4096 + wbyte);
        gload_lds16(vbase + ((long)kt << 12) + ((long)rr << 6) + sel,
                    (char*)Vs + c * 4096 + wbyte);
      }
    }
    __syncthreads();  // staging complete (drains vmcnt)

    // ---- phase B1: ka frags, c2p (10 MFMA) -> c2p_w, S (8 MFMA) -------------
    bf16x8 ka[2];
    ka[0] = lds_frag(Ks, wave * 16 + fr, fq);
    ka[1] = lds_frag(Ks, wave * 16 + fr, 4 + fq);
    __builtin_amdgcn_s_setprio(1);
    {
      f32x4 cw[5];
#pragma unroll
      for (int t = 0; t < 5; t++) cw[t] = f32x4{0.f, 0.f, 0.f, 0.f};
#pragma unroll
      for (int kc = 0; kc < 2; kc++)
#pragma unroll
        for (int t = 0; t < 5; t++) {
          const bf16x8 pb = lds_frag(PX, wave * 16 + t * 16 + fr, kc * 4 + fq);
          cw[t] = __builtin_amdgcn_mfma_f32_16x16x32_bf16(qa[kc], pb, cw[t], 0, 0, 0);
        }
#pragma unroll
      for (int t = 0; t < 5; t++) {
        bf16x4 pk;
#pragma unroll
        for (int r = 0; r < 4; r++) pk[r] = (bf16)cw[t][r];
        *(bf16x4*)&c2p_w[(t * 16 + fr) * 20 + fq * 4] = pk;  // [t2][qi]
      }
    }
    f32x4 s[4];
#pragma unroll
    for (int n = 0; n < 4; n++) s[n] = f32x4{0.f, 0.f, 0.f, 0.f};
#pragma unroll
    for (int kc = 0; kc < 2; kc++)
#pragma unroll
      for (int n = 0; n < 4; n++) {
        const bf16x8 kb = lds_frag(Ks, n * 16 + fr, kc * 4 + fq);
        s[n] = __builtin_amdgcn_mfma_f32_16x16x32_bf16(qa[kc], kb, s[n], 0, 0, 0);
      }
    __builtin_amdgcn_s_setprio(0);
    __syncthreads();  // PXk consumed -> PX free for PXq

    // ---- phase A2: stage PXq window into PX ---------------------------------
    {
      const int j0q = k0 - q0 + 449;
#pragma unroll
      for (int c = 0; c < 4; c++) {
        const int u = c * 256 + tid;
        const int rr = u >> 3;
        const int sel = (((u & 7) ^ (rr & 7)) << 3);
        int jq = j0q + rr;
        jq = jq < 0 ? 0 : (jq > 1023 ? 1023 : jq);
        gload_lds16(posq + ((long)jq << 6) + sel, (char*)PX + c * 4096 + wbyte);
      }
    }
    __syncthreads();  // staging complete

    // ---- phase B2: p2c (10 MFMA) -> p2c_P window-packed ---------------------
    __builtin_amdgcn_s_setprio(1);
    {
      f32x4 pw[5];
#pragma unroll
      for (int t = 0; t < 5; t++) pw[t] = f32x4{0.f, 0.f, 0.f, 0.f};
#pragma unroll
      for (int kc = 0; kc < 2; kc++)
#pragma unroll
        for (int t = 0; t < 5; t++) {
          const bf16x8 pb = lds_frag(PX, (wave + t) * 16 + fr, kc * 4 + fq);
          pw[t] = __builtin_amdgcn_mfma_f32_16x16x32_bf16(ka[kc], pb, pw[t], 0, 0, 0);
        }
#pragma unroll
      for (int t = 0; t < 5; t++) {
#pragma unroll
        for (int r = 0; r < 4; r++) {
          // tp = (wave+t)*16+fr, ki = wave*16+fq*4+r, toff = tp-ki
          const int toff = t * 16 + fr - fq * 4 - r;
          if ((unsigned)toff < 64u)
            p2c_P[(wave * 16 + fq * 4 + r) * 68 + toff] = (bf16)pw[t][r];
        }
      }
    }
    __builtin_amdgcn_s_setprio(0);
    __syncthreads();  // p2c_P visible; PXq dead (p_l may overwrite)

    // ---- phase D: gathers, defer-max softmax, p_l, PV -----------------------
    bf16x8 vb[2][4];
#pragma unroll
    for (int kc = 0; kc < 2; kc++)
#pragma unroll
      for (int n = 0; n < 4; n++) vb[kc][n] = lds_frag(Vs, n * 16 + fr, kc * 4 + fq);

    float st[4][4];
#pragma unroll
    for (int n = 0; n < 4; n++) {
      const int ki = n * 16 + fr;
      const float mb = (1.0f - mask[b * S_ + k0 + ki]) * (-1e9f * LOG2E_);
#pragma unroll
      for (int r = 0; r < 4; r++) {
        const int qi_s = fq * 4 + r;
        const float cv = (float)c2p_w[(qi_s - ki + 63) * 20 + qi_s];
        // toff = 63 - qi_rel (independent of ki)
        const float pv = (float)p2c_P[ki * 68 + (63 - (wave * 16 + qi_s))];
        st[n][r] = (s[n][r] + cv + pv) * SCL2_ + mb;  // log2 domain
      }
    }

    float pmax[4];
#pragma unroll
    for (int r = 0; r < 4; r++) {
      float v = fmaxf(fmaxf(st[0][r], st[1][r]), fmaxf(st[2][r], st[3][r]));
      pmax[r] = rowMax16(v);
    }
    const bool ok = (pmax[0] - m_r[0] <= THR2_) && (pmax[1] - m_r[1] <= THR2_) &&
                    (pmax[2] - m_r[2] <= THR2_) && (pmax[3] - m_r[3] <= THR2_);
    if (!__all(ok)) {
#pragma unroll
      for (int r = 0; r < 4; r++) {
        const float mn = fmaxf(m_r[r], pmax[r]);
        const float sc = exp2f(m_r[r] - mn);
        m_r[r] = mn;
        l_r[r] *= sc;
#pragma unroll
        for (int n = 0; n < 4; n++) o[n][r] *= sc;
      }
    }
    float rs[4] = {0.f, 0.f, 0.f, 0.f};
#pragma unroll
    for (int n = 0; n < 4; n++) {
      const int ki = n * 16 + fr;
#pragma unroll
      for (int r = 0; r < 4; r++) {
        const int qi_s = fq * 4 + r;
        const float p = exp2f(st[n][r] - m_r[r]);
        rs[r] += p;
        *(bf16*)(pl_base + qi_s * 128 + ((ki * 2) ^ ((qi_s & 7) << 4))) = (bf16)p;
      }
    }
#pragma unroll
    for (int r = 0; r < 4; r++) l_r[r] += rowSum16(rs[r]);

#pragma unroll
    for (int kc = 0; kc < 2; kc++) {
      const bf16x8 pa =
          *(const bf16x8*)(pl_base + fr * 128 + ((kc * 64 + fq * 16) ^ ((fr & 7) << 4)));
#pragma unroll
      for (int n = 0; n < 4; n++)
        o[n] = __builtin_amdgcn_mfma_f32_16x16x32_bf16(pa, vb[kc][n], o[n], 0, 0, 0);
    }
  }

  // ---- epilogue ----
#pragma unroll
  for (int r = 0; r < 4; r++) {
    const float inv = 1.f / l_r[r];
    const long row = (long)(b * S_ + q0 + wave * 16 + fq * 4 + r) * D_ + h * 64;
#pragma unroll
    for (int n = 0; n < 4; n++) ctx[row + n * 16 + fr] = (bf16)(o[n][r] * inv);
  }
}

// ------- weight transpose+convert, 4 square weights in one dispatch ---------
__global__ __launch_bounds__(256) void wtrans4(const float* __restrict__ Wq,
                                               const float* __restrict__ Wk,
                                               const float* __restrict__ Wv,
                                               const float* __restrict__ Wo,
                                               bf16* __restrict__ wqkvT,
                                               bf16* __restrict__ woT) {
  const int z = blockIdx.z;
  const int l = z >> 2, which = z & 3;
  const long DD = (long)D_ * D_;
  const float* W = (which == 0 ? Wq : which == 1 ? Wk : which == 2 ? Wv : Wo) + l * DD;
  bf16* WT = (which < 3) ? (wqkvT + (long)l * 3 * DD + which * DD) : (woT + (long)l * DD);
  __shared__ float t[32][33];
  const int n0 = blockIdx.x * 32, k0 = blockIdx.y * 32;
  const int tx = threadIdx.x & 31, ty = threadIdx.x >> 5;
#pragma unroll
  for (int i = ty; i < 32; i += 8) t[i][tx] = W[(long)(k0 + i) * D_ + n0 + tx];
  __syncthreads();
#pragma unroll
  for (int i = ty; i < 32; i += 8) WT[(long)(n0 + i) * D_ + k0 + tx] = (bf16)t[tx][i];
}

// ------- weight transpose+convert: W[K,N] f32 -> WT[N,K] bf16, z-batched ----
__global__ __launch_bounds__(256) void wtrans(const float* __restrict__ W,
                                              bf16* __restrict__ WT, int K, int N,
                                              long sW, long sT) {
  W += (long)blockIdx.z * sW;
  WT += (long)blockIdx.z * sT;
  __shared__ float t[32][33];
  const int n0 = blockIdx.x * 32, k0 = blockIdx.y * 32;
  const int tx = threadIdx.x & 31, ty = threadIdx.x >> 5;
#pragma unroll
  for (int i = ty; i < 32; i += 8) t[i][tx] = W[(long)(k0 + i) * N + n0 + tx];
  __syncthreads();
#pragma unroll
  for (int i = ty; i < 32; i += 8) WT[(long)(n0 + i) * K + k0 + tx] = (bf16)t[tx][i];
}

__global__ __launch_bounds__(256) void f2b(const float* __restrict__ in,
                                           bf16* __restrict__ out, long n) {
  long i = (long)blockIdx.x * 256 + threadIdx.x;
  if (i < n) out[i] = (bf16)in[i];
}

__global__ __launch_bounds__(256) void bias_concat(const float* __restrict__ bq,
                                                   const float* __restrict__ bk,
                                                   const float* __restrict__ bv,
                                                   float* __restrict__ bqkv) {
  const int i = blockIdx.x * 256 + threadIdx.x;
  const int l = i / (3 * D_), s = (i % (3 * D_)) / D_, d = i % D_;
  const float* src = s == 0 ? bq : (s == 1 ? bk : bv);
  bqkv[i] = src[l * D_ + d];
}

// ---------------- embedding + LN + mask (f32x4 vectorized) ------------------
__global__ __launch_bounds__(256) void embed_ln(
    const int* __restrict__ ids, const int* __restrict__ segs,
    const float* __restrict__ mask, const float* __restrict__ tok,
    const float* __restrict__ seg, const float* __restrict__ g,
    const float* __restrict__ bta, float* __restrict__ h, bf16* __restrict__ hb) {
  __shared__ float r1[4], r2[4];
  const int t = blockIdx.x;
  const int d4 = threadIdx.x;
  const long tb4 = (long)ids[t] * 256;
  const long sb4 = (long)segs[t] * 256;
  const long b4 = (long)t * 256;
  f32x4 x = ((const f32x4*)tok)[tb4 + d4];
  const f32x4 sv = ((const f32x4*)seg)[sb4 + d4];
#pragma unroll
  for (int r = 0; r < 4; r++) x[r] += sv[r];
  float sm = x[0] + x[1] + x[2] + x[3];
  sm = blockSum4(sm, r1);
  const float mean = sm * (1.f / D_);
  float vs = 0.f;
#pragma unroll
  for (int r = 0; r < 4; r++) {
    const float c = x[r] - mean;
    vs += c * c;
  }
  vs = blockSum4(vs, r2);
  const float rstd = rsqrtf(vs * (1.f / D_) + 1e-12f);
  const float mk = mask[t];
  const f32x4 gv = ((const f32x4*)g)[d4];
  const f32x4 bv = ((const f32x4*)bta)[d4];
  f32x4 y;
  bf16x4 yb;
#pragma unroll
  for (int r = 0; r < 4; r++) {
    y[r] = ((x[r] - mean) * rstd * gv[r] + bv[r]) * mk;
    yb[r] = (bf16)y[r];
  }
  ((f32x4*)h)[b4 + d4] = y;
  *(bf16x4*)&hb[(b4 + d4) * 4] = yb;
}

// --- residual + split-K reduce + bias + LN (fused, f32x4 vectorized) --------
template <int P>
__global__ __launch_bounds__(256) void ln_residual_red(
    const float* __restrict__ hin, float* __restrict__ hout,
    const float* __restrict__ part, long pstride4,
    const float* __restrict__ bias, const float* __restrict__ g,
    const float* __restrict__ bta, bf16* __restrict__ hb) {
  __shared__ float r1[4], r2[4];
  const int d4 = threadIdx.x;
  const long b4 = (long)blockIdx.x * 256;
  f32x4 x = ((const f32x4*)hin)[b4 + d4];
  const f32x4 bi = ((const f32x4*)bias)[d4];
#pragma unroll
  for (int r = 0; r < 4; r++) x[r] += bi[r];
#pragma unroll
  for (int z = 0; z < P; z++) {
    const f32x4 pv = ((const f32x4*)part)[(long)z * pstride4 + b4 + d4];
#pragma unroll
    for (int r = 0; r < 4; r++) x[r] += pv[r];
  }
  float sm = x[0] + x[1] + x[2] + x[3];
  sm = blockSum4(sm, r1);
  const float mean = sm * (1.f / D_);
  float vs = 0.f;
#pragma unroll
  for (int r = 0; r < 4; r++) {
    const float c = x[r] - mean;
    vs += c * c;
  }
  vs = blockSum4(vs, r2);
  const float rstd = rsqrtf(vs * (1.f / D_) + 1e-12f);
  const f32x4 gv = ((const f32x4*)g)[d4];
  const f32x4 bv = ((const f32x4*)bta)[d4];
  f32x4 y;
  bf16x4 yb;
#pragma unroll
  for (int r = 0; r < 4; r++) {
    y[r] = (x[r] - mean) * rstd * gv[r] + bv[r];
    yb[r] = (bf16)y[r];
  }
  ((f32x4*)hout)[b4 + d4] = y;
  *(bf16x4*)&hb[(b4 + d4) * 4] = yb;
}

// ============================================================================
extern "C" void kernel_launch(void* const* d_in, const int* in_sizes, int n_in,
                              void* d_out, int out_size, void* d_ws, size_t ws_size,
                              hipStream_t stream) {
  (void)in_sizes; (void)n_in; (void)out_size; (void)ws_size;
  const int* input_ids = (const int*)d_in[0];
  const int* segment_ids = (const int*)d_in[1];
  const float* attention_mask = (const float*)d_in[2];
  const float* tok_emb = (const float*)d_in[3];
  const float* seg_emb = (const float*)d_in[4];
  const float* emb_ln_g = (const float*)d_in[5];
  const float* emb_ln_b = (const float*)d_in[6];
  const float* rel_emb = (const float*)d_in[7];
  const float* Wq = (const float*)d_in[8];
  const float* bq = (const float*)d_in[9];
  const float* Wk = (const float*)d_in[10];
  const float* bk = (const float*)d_in[11];
  const float* Wv = (const float*)d_in[12];
  const float* bv = (const float*)d_in[13];
  const float* Wo = (const float*)d_in[14];
  const float* bo = (const float*)d_in[15];
  const float* ln1_g = (const float*)d_in[16];
  const float* ln1_b = (const float*)d_in[17];
  const float* W1 = (const float*)d_in[18];
  const float* b1 = (const float*)d_in[19];
  const float* W2 = (const float*)d_in[20];
  const float* b2 = (const float*)d_in[21];
  const float* ln2_g = (const float*)d_in[22];
  const float* ln2_b = (const float*)d_in[23];

  const long DD = (long)D_ * D_;
  const long DF = (long)D_ * F_;
  const int D3 = 3 * D_;

  char* ws = (char*)d_ws;
  auto alloc = [&](size_t bytes) {
    char* p = ws;
    ws += (bytes + 255) & ~(size_t)255;
    return p;
  };
  bf16* wqkvT = (bf16*)alloc((size_t)L_ * 3 * DD * 2);
  bf16* woT = (bf16*)alloc((size_t)L_ * DD * 2);
  bf16* w1T = (bf16*)alloc((size_t)L_ * DF * 2);
  bf16* w2T = (bf16*)alloc((size_t)L_ * DF * 2);
  float* bqkv = (float*)alloc((size_t)L_ * 3 * D_ * 4);
  bf16* relb = (bf16*)alloc((size_t)2 * SPAN_ * D_ * 2);
  float* hbuf = (float*)alloc((size_t)B_ * S_ * D_ * 4);
  bf16* hb = (bf16*)alloc((size_t)B_ * S_ * D_ * 2);
  bf16* qkv = (bf16*)alloc((size_t)B_ * S_ * 3 * D_ * 2);
  bf16* kp = (bf16*)alloc((size_t)B_ * H_ * S_ * DH_ * 2);
  bf16* vp = (bf16*)alloc((size_t)B_ * H_ * S_ * DH_ * 2);
  bf16* pospk = (bf16*)alloc((size_t)L_ * POSL_ * 2);
  bf16* ctxb = (bf16*)alloc((size_t)B_ * S_ * D_ * 2);
  bf16* ff1b = (bf16*)alloc((size_t)B_ * S_ * F_ * 2);
  float* kpart = (float*)alloc((size_t)4 * B_ * S_ * D_ * 4);
  const long PSTR = (long)B_ * S_ * D_;

  // ---- one-time per call ----
  wtrans4<<<dim3(D_ / 32, D_ / 32, 4 * L_), 256, 0, stream>>>(Wq, Wk, Wv, Wo, wqkvT, woT);
  wtrans<<<dim3(F_ / 32, D_ / 32, L_), 256, 0, stream>>>(W1, w1T, D_, F_, DF, DF);
  wtrans<<<dim3(D_ / 32, F_ / 32, L_), 256, 0, stream>>>(W2, w2T, F_, D_, DF, DF);
  bias_concat<<<dim3(L_ * 3 * D_ / 256), 256, 0, stream>>>(bq, bk, bv, bqkv);
  f2b<<<dim3((2 * SPAN_ * D_) / 256), 256, 0, stream>>>(rel_emb, relb, (long)2 * SPAN_ * D_);
  gemm_bt<5><<<dim3((2 * D_) / 128, (2 * SPAN_) / 128, L_), 256, 0, stream>>>(
      relb, wqkvT, bqkv, pospk, 2 * SPAN_, 2 * D_, D_, D_, D_, 0, 1.f,
      0, 3 * DD, POSL_, 3 * D_);
  embed_ln<<<dim3(B_ * S_), 256, 0, stream>>>(input_ids, segment_ids, attention_mask,
                                              tok_emb, seg_emb, emb_ln_g, emb_ln_b, hbuf, hb);

  const size_t SH = 131072;  // 128 KiB dynamic LDS for gemm256

  for (int l = 0; l < L_; ++l) {
    const bf16* wqkv_ = wqkvT + (long)l * 3 * DD;
    const bf16* wo_ = woT + (long)l * DD;
    const bf16* w1_ = w1T + (long)l * DF;
    const bf16* w2_ = w2T + (long)l * DF;
    const float* bqkv_ = bqkv + (long)l * 3 * D_;
    const float* bo_ = bo + (long)l * D_;
    const float* b1_ = b1 + (long)l * F_;
    const float* b2_ = b2 + (long)l * D_;

    // fused q,k,v projection: qkv[B*S, 3D]  (128-tile, 768 blocks = 3/CU)
    gemm_bt<3><<<dim3(D3 / 128, (B_ * S_) / 128, 1), 256, 0, stream>>>(
        hb, wqkv_, bqkv_, qkv, B_ * S_, D3, D_, D_, D_, D3, 1.f, 0, 0, 0, 0);
    repack_kv<<<dim3(16, B_ * H_), 256, 0, stream>>>(qkv, kp, vp);

    // fused attention (5-phase, 54272 B LDS -> 3 blocks/CU)
    attn_fused<<<dim3(1024), 256, 0, stream>>>(qkv, kp, vp, pospk + (long)l * POSL_,
                                               attention_mask, ctxb);

    // attention output projection: split-K2 128-tile (512 blocks = 2/CU)
    gemm_bt<0><<<dim3(D_ / 128, (B_ * S_) / 128, 2), 256, 0, stream>>>(
        ctxb, wo_, nullptr, kpart, B_ * S_, D_, D_ / 2, D_, D_, D_, 1.f,
        D_ / 2, D_ / 2, PSTR, 0);
    ln_residual_red<2><<<dim3(B_ * S_), 256, 0, stream>>>(
        hbuf, hbuf, kpart, PSTR / 4, bo_, ln1_g + l * D_, ln1_b + l * D_, hb);

    // FFN
    gemm256<4><<<dim3(F_ / 256, (B_ * S_) / 256, 1), 512, SH, stream>>>(
        hb, w1_, b1_, ff1b, D_, D_, D_, F_, 0, 0, 0);
    gemm256<0><<<dim3(D_ / 256, (B_ * S_) / 256, 4), 512, SH, stream>>>(
        ff1b, w2_, nullptr, kpart, F_ / 4, F_, F_, D_, F_ / 4, F_ / 4, PSTR);
    float* hout = (l == L_ - 1) ? (float*)d_out : hbuf;
    ln_residual_red<4><<<dim3(B_ * S_), 256, 0, stream>>>(
        hbuf, hout, kpart, PSTR / 4, b2_, ln2_g + l * D_, ln2_b + l * D_, hb);
  }
}

// Round 16
// 1265.219 us; speedup vs baseline: 1.0509x; 1.0509x over previous
//
#include <hip/hip_runtime.h>

#define DEV __device__ __forceinline__

typedef __bf16 bf16;
typedef __bf16 bf16x4 __attribute__((ext_vector_type(4)));
typedef __bf16 bf16x8 __attribute__((ext_vector_type(8)));
typedef float f32x4 __attribute__((ext_vector_type(4)));

constexpr int B_ = 4, S_ = 1024, D_ = 1024, H_ = 16, F_ = 4096, L_ = 4, SPAN_ = 512, DH_ = 64;
constexpr float SCALE_ = 0.07216878364870322f;  // 1/sqrt(3*DH)
constexpr float LOG2E_ = 1.4426950408889634f;
constexpr float SCL2_ = SCALE_ * LOG2E_;
constexpr float THR2_ = 11.5f;  // defer-max threshold in log2 units (~8 nats)
constexpr long POSL_ = 32L * 1024 * 64;  // pospk elements per layer

DEV void gload_lds16(const void* g, void* l) {
  __builtin_amdgcn_global_load_lds((const __attribute__((address_space(1))) void*)g,
                                   (__attribute__((address_space(3))) void*)l, 16, 0, 0);
}

// DPP cross-lane within 16-lane rows (VALU, not LDS pipe)
template <int CTRL>
DEV float dppf(float x) {
  return __builtin_bit_cast(
      float, __builtin_amdgcn_mov_dpp(__builtin_bit_cast(int, x), CTRL, 0xf, 0xf, true));
}
DEV float rowMax16(float v) {
  v = fmaxf(v, dppf<0x128>(v));
  v = fmaxf(v, dppf<0x124>(v));
  v = fmaxf(v, dppf<0x122>(v));
  v = fmaxf(v, dppf<0x121>(v));
  return v;
}
DEV float rowSum16(float v) {
  v += dppf<0x128>(v);
  v += dppf<0x124>(v);
  v += dppf<0x122>(v);
  v += dppf<0x121>(v);
  return v;
}

DEV float blockSum4(float v, volatile float* red) {
#pragma unroll
  for (int o = 32; o; o >>= 1) v += __shfl_xor(v, o);
  if ((threadIdx.x & 63) == 0) red[threadIdx.x >> 6] = v;
  __syncthreads();
  return red[0] + red[1] + red[2] + red[3];
}

// swizzled MFMA-fragment read from a [rows][64] bf16 LDS tile (128 B rows)
DEV bf16x8 lds_frag(const bf16* buf, int row, int chunk) {
  return *(const bf16x8*)((const char*)buf + row * 128 + ((chunk ^ (row & 7)) << 4));
}
DEV bf16x8 rdfrag(const char* base, int row, int chunk) {
  return *(const bf16x8*)(base + row * 128 + ((chunk ^ (row & 7)) << 4));
}

// ============ 256x256 deep-pipelined GEMM: C = A[M,K] @ B^T, BK=64 ==========
// EPI: 0 f32 | 3 bf16+bias | 4 bf16 gelu+bias | 6 bf16 raw (split-K partial)
template <int EPI>
__global__ __launch_bounds__(512, 1) void gemm256(
    const bf16* __restrict__ A, const bf16* __restrict__ Bm,
    const float* __restrict__ bias, void* __restrict__ Cout,
    int K, int lda, int ldb, int ldc, long sA, long sB, long sC) {
  extern __shared__ __align__(16) char smem[];  // A dbuf [2][256][64] @0, B @65536

  const int z = blockIdx.z;
  A += (long)z * sA;
  Bm += (long)z * sB;
  const long coff = (long)z * sC;

  const int nwg = gridDim.x * gridDim.y;
  const int flat = blockIdx.y * gridDim.x + blockIdx.x;
  const int qq = nwg >> 3;
  const int swz = (flat & 7) * qq + (flat >> 3);
  const int bx = swz % gridDim.x, by = swz / gridDim.x;
  const int m0 = by * 256, n0 = bx * 256;

  const int tid = threadIdx.x, lane = tid & 63, wave = tid >> 6;
  const int wr = wave >> 2, wc = wave & 3;
  const int fr = lane & 15, fq = lane >> 4;

  f32x4 acc[8][4];
#pragma unroll
  for (int m = 0; m < 8; m++)
#pragma unroll
    for (int n = 0; n < 4; n++) acc[m][n] = f32x4{0.f, 0.f, 0.f, 0.f};

  const int r8 = tid >> 3;
  const int swzel = ((tid & 7) ^ (r8 & 7)) << 3;
  const bf16* ga = A + (long)(m0 + r8) * lda + swzel;
  const bf16* gb = Bm + (long)(n0 + r8) * ldb + swzel;

  const int NT = K >> 6;

  auto stage = [&](int t) {
    const long ko = (long)t * 64;
    char* da = smem + ((t & 1) << 15) + wave * 1024;
    gload_lds16(ga + ko, da);
    gload_lds16(ga + 64 * (long)lda + ko, da + 8192);
    gload_lds16(ga + 128 * (long)lda + ko, da + 16384);
    gload_lds16(ga + 192 * (long)lda + ko, da + 24576);
    char* db = smem + 65536 + ((t & 1) << 15) + wave * 1024;
    gload_lds16(gb + ko, db);
    gload_lds16(gb + 64 * (long)ldb + ko, db + 8192);
    gload_lds16(gb + 128 * (long)ldb + ko, db + 16384);
    gload_lds16(gb + 192 * (long)ldb + ko, db + 24576);
  };

  stage(0);
  asm volatile("s_waitcnt vmcnt(0)" ::: "memory");
  __builtin_amdgcn_s_barrier();

  for (int j = 0; j < NT; j++) {
    const char* Ac = smem + ((j & 1) << 15);
    const char* Bc = smem + 65536 + ((j & 1) << 15);

    if (j + 1 < NT) stage(j + 1);

    bf16x8 af[4][2], bfg[4][2];
#pragma unroll
    for (int m = 0; m < 4; m++) {
      const int ar = wr * 128 + m * 16 + fr;
      af[m][0] = rdfrag(Ac, ar, fq);
      af[m][1] = rdfrag(Ac, ar, 4 + fq);
    }
#pragma unroll
    for (int n = 0; n < 4; n++) {
      const int br = wc * 64 + n * 16 + fr;
      bfg[n][0] = rdfrag(Bc, br, fq);
      bfg[n][1] = rdfrag(Bc, br, 4 + fq);
    }

    __builtin_amdgcn_s_setprio(1);
#pragma unroll
    for (int m = 0; m < 4; m++)
#pragma unroll
      for (int n = 0; n < 4; n++)
#pragma unroll
        for (int kc = 0; kc < 2; kc++)
          acc[m][n] = __builtin_amdgcn_mfma_f32_16x16x32_bf16(af[m][kc], bfg[n][kc],
                                                              acc[m][n], 0, 0, 0);
    __builtin_amdgcn_s_setprio(0);
    __builtin_amdgcn_sched_barrier(0);

#pragma unroll
    for (int m = 0; m < 4; m++) {
      const int ar = wr * 128 + (m + 4) * 16 + fr;
      af[m][0] = rdfrag(Ac, ar, fq);
      af[m][1] = rdfrag(Ac, ar, 4 + fq);
    }
    __builtin_amdgcn_s_setprio(1);
#pragma unroll
    for (int m = 0; m < 4; m++)
#pragma unroll
      for (int n = 0; n < 4; n++)
#pragma unroll
        for (int kc = 0; kc < 2; kc++)
          acc[m + 4][n] = __builtin_amdgcn_mfma_f32_16x16x32_bf16(af[m][kc], bfg[n][kc],
                                                                  acc[m + 4][n], 0, 0, 0);
    __builtin_amdgcn_s_setprio(0);

    asm volatile("s_waitcnt vmcnt(0)" ::: "memory");
    __builtin_amdgcn_s_barrier();
  }

#pragma unroll
  for (int m = 0; m < 8; m++) {
#pragma unroll
    for (int n = 0; n < 4; n++) {
      const int col = n0 + wc * 64 + n * 16 + fr;
      float bval = 0.f;
      if constexpr (EPI == 3 || EPI == 4) bval = bias ? bias[col] : 0.f;
#pragma unroll
      for (int rr = 0; rr < 4; rr++) {
        const int row = m0 + wr * 128 + m * 16 + fq * 4 + rr;
        const long idx = coff + (long)row * ldc + col;
        const float v = acc[m][n][rr];
        if constexpr (EPI == 0) ((float*)Cout)[idx] = v;
        else if constexpr (EPI == 3) ((bf16*)Cout)[idx] = (bf16)(v + bval);
        else if constexpr (EPI == 4) {
          float x = v + bval;
          x = 0.5f * x * (1.f + erff(x * 0.70710678118654752f));
          ((bf16*)Cout)[idx] = (bf16)x;
        } else if constexpr (EPI == 6) {
          ((bf16*)Cout)[idx] = (bf16)v;
        }
      }
    }
  }
}

// ------ 128-tile GEMM (pos EPI=5; Wo split-K EPI=6 bf16; QKV EPI=3) ---------
template <int EPI>
__global__ __launch_bounds__(256) void gemm_bt(
    const bf16* __restrict__ A, const bf16* __restrict__ Bm,
    const float* __restrict__ bias, void* __restrict__ Cout,
    int M, int N, int K, int lda, int ldb, int ldc, float alpha,
    long sA, long sB, long sC, long sBias) {
  __shared__ alignas(16) bf16 As[128 * 64];
  __shared__ alignas(16) bf16 Bs[128 * 64];

  const int z = blockIdx.z;
  A += (long)z * sA;
  Bm += (long)z * sB;
  bias += (long)z * sBias;
  const long coff = (long)z * sC;

  const int nwg = gridDim.x * gridDim.y;
  const int flat = blockIdx.y * gridDim.x + blockIdx.x;
  const int qq = nwg >> 3;
  const int swz = (flat & 7) * qq + (flat >> 3);
  const int bx = swz % gridDim.x, by = swz / gridDim.x;

  const int m0 = by * 128, n0 = bx * 128;
  const int tid = threadIdx.x, lane = tid & 63, wave = tid >> 6;
  const int wr = wave >> 1, wc = wave & 1;
  const int fr = lane & 15, fq = lane >> 4;

  f32x4 acc[4][4];
#pragma unroll
  for (int m = 0; m < 4; m++)
#pragma unroll
    for (int n = 0; n < 4; n++) acc[m][n] = f32x4{0.f, 0.f, 0.f, 0.f};

  const int r8 = tid >> 3;
  const int swzel = ((tid & 7) ^ (r8 & 7)) << 3;
  const bf16* ga = A + (long)(m0 + r8) * lda + swzel;
  const bf16* gb = Bm + (long)(n0 + r8) * ldb + swzel;
  const int swzrd = fr & 7;

  for (int k0 = 0; k0 < K; k0 += 64) {
#pragma unroll
    for (int i = 0; i < 4; i++)
      gload_lds16(ga + (long)i * 32 * lda + k0, (char*)As + i * 4096 + wave * 1024);
#pragma unroll
    for (int i = 0; i < 4; i++)
      gload_lds16(gb + (long)i * 32 * ldb + k0, (char*)Bs + i * 4096 + wave * 1024);
    __syncthreads();
#pragma unroll
    for (int kc = 0; kc < 2; kc++) {
      bf16x8 af[4], bfv[4];
#pragma unroll
      for (int m = 0; m < 4; m++)
        af[m] = *(const bf16x8*)((char*)As + (wr * 64 + m * 16 + fr) * 128 +
                                 (((kc * 4 + fq) ^ swzrd) << 4));
#pragma unroll
      for (int n = 0; n < 4; n++)
        bfv[n] = *(const bf16x8*)((char*)Bs + (wc * 64 + n * 16 + fr) * 128 +
                                  (((kc * 4 + fq) ^ swzrd) << 4));
#pragma unroll
      for (int m = 0; m < 4; m++)
#pragma unroll
        for (int n = 0; n < 4; n++)
          acc[m][n] = __builtin_amdgcn_mfma_f32_16x16x32_bf16(af[m], bfv[n], acc[m][n], 0, 0, 0);
    }
    __syncthreads();
  }

#pragma unroll
  for (int m = 0; m < 4; m++) {
#pragma unroll
    for (int n = 0; n < 4; n++) {
      const int col = n0 + wc * 64 + n * 16 + fr;
      float bval = 0.f;
      if constexpr (EPI == 3 || EPI == 4 || EPI == 5) bval = bias ? bias[col] : 0.f;
#pragma unroll
      for (int rr = 0; rr < 4; rr++) {
        const int row = m0 + wr * 64 + m * 16 + fq * 4 + rr;
        const long idx = coff + (long)row * ldc + col;
        const float v = acc[m][n][rr];
        if constexpr (EPI == 0) ((float*)Cout)[idx] = v * alpha;
        else if constexpr (EPI == 3) ((bf16*)Cout)[idx] = (bf16)(v + bval);
        else if constexpr (EPI == 4) {
          float x = v + bval;
          x = 0.5f * x * (1.f + erff(x * 0.70710678118654752f));
          ((bf16*)Cout)[idx] = (bf16)x;
        } else if constexpr (EPI == 5) {
          const long pidx = coff + ((long)(col >> 6) * 1024 + row) * 64 + (col & 63);
          ((bf16*)Cout)[pidx] = (bf16)(v + bval);
        } else if constexpr (EPI == 6) {
          ((bf16*)Cout)[idx] = (bf16)v;
        }
      }
    }
  }
}

// ---- repack: k-section of qkv -> kp[bh][s][64]; v-section -> vp[bh][kt][dh][64]
__global__ __launch_bounds__(256) void repack_kv(const bf16* __restrict__ qkv,
                                                 bf16* __restrict__ kp,
                                                 bf16* __restrict__ vp) {
  const int kt = blockIdx.x, bh = blockIdx.y;
  const int b = bh >> 4, h = bh & 15;
  const int k0 = kt * 64;
  __shared__ bf16 t[64][72];
  const int ty = threadIdx.x >> 3, tx = threadIdx.x & 7;
#pragma unroll
  for (int p = 0; p < 2; p++) {
    const int s = k0 + p * 32 + ty;
    const long base = (long)(b * 1024 + s) * 3072 + h * 64;
    bf16x8 kv = *(const bf16x8*)(qkv + base + 1024 + tx * 8);
    *(bf16x8*)(kp + ((long)(bh * 1024 + s) << 6) + tx * 8) = kv;
    bf16x8 vv = *(const bf16x8*)(qkv + base + 2048 + tx * 8);
    *(bf16x8*)(&t[p * 32 + ty][tx * 8]) = vv;
  }
  __syncthreads();
  const int dh = threadIdx.x >> 2, sc = (threadIdx.x & 3) * 16;
  bf16 tmp[16];
#pragma unroll
  for (int j = 0; j < 16; j++) tmp[j] = t[sc + j][dh];
  bf16* dst = vp + ((long)(bh * 16 + kt) << 12) + dh * 64 + sc;
  *(bf16x8*)dst = *(bf16x8*)tmp;
  *(bf16x8*)(dst + 8) = *(bf16x8*)(tmp + 8);
}

// ============== fused attention: QK^T + rel-pos bias + softmax + PV =========
// 3 barriers/ktile: A(stage) | B(c2p + S + p2c, 28-MFMA cluster) | D(softmax+PV)
__global__ __launch_bounds__(256) void attn_fused(
    const bf16* __restrict__ qkv, const bf16* __restrict__ kp,
    const bf16* __restrict__ vp, const bf16* __restrict__ pospk,
    const float* __restrict__ mask, bf16* __restrict__ ctx) {
  const int id = blockIdx.x;
  const int xcd = id & 7, sub = id >> 3;
  const int bh = xcd + 8 * (sub >> 4);
  const int qt = sub & 15;
  const int b = bh >> 4, h = bh & 15;
  const int q0 = qt * 64;
  const int tid = threadIdx.x, wave = tid >> 6, lane = tid & 63;
  const int fr = lane & 15, fq = lane >> 4;

  // LDS (79360 B, 2 blocks/CU) — r14-proven envelope
  __shared__ alignas(16) char smem[79360];
  bf16* PXk = (bf16*)smem;
  char* p_l = smem;
  bf16* PXq = (bf16*)(smem + 16384);
  bf16* Ks = (bf16*)(smem + 32768);
  bf16* Vs = (bf16*)(smem + 40960);
  bf16* c2p_T = (bf16*)(smem + 49152);
  bf16* p2c_T = (bf16*)(smem + 61952);

  const bf16* posq = pospk + ((long)h << 16);
  const bf16* posk = pospk + ((long)(16 + h) << 16);
  const bf16* kbase = kp + ((long)bh << 16);
  const bf16* vbase = vp + ((long)bh << 16);

  bf16x8 qa[2];
  {
    const bf16* qrow = qkv + (long)(b * 1024 + q0 + wave * 16 + fr) * 3072 + h * 64;
    qa[0] = *(const bf16x8*)(qrow + fq * 8);
    qa[1] = *(const bf16x8*)(qrow + 32 + fq * 8);
  }

  f32x4 o[4];
#pragma unroll
  for (int n = 0; n < 4; n++) o[n] = f32x4{0.f, 0.f, 0.f, 0.f};
  float m_r[4], l_r[4];
#pragma unroll
  for (int r = 0; r < 4; r++) { m_r[r] = -1e30f; l_r[r] = 0.f; }

  char* pl_base = p_l + wave * 2048;
  bf16* c2p_w = c2p_T + wave * 1600;  // [80][20]
  const int wbyte = wave * 1024;

  for (int kt = 0; kt < 16; kt++) {
    const int k0 = kt * 64;

    // ---- phase A: stage PXk, PXq, K, V (12 gload_lds16/thread) -------------
    __syncthreads();
    {
      const int j0k = q0 - k0 + 449;
      const int j0q = k0 - q0 + 449;
#pragma unroll
      for (int c = 0; c < 4; c++) {
        const int u = c * 256 + tid;
        const int rr = u >> 3;
        const int sel = (((u & 7) ^ (rr & 7)) << 3);
        int jk = j0k + rr;
        jk = jk < 0 ? 0 : (jk > 1023 ? 1023 : jk);
        gload_lds16(posk + ((long)jk << 6) + sel, (char*)PXk + c * 4096 + wbyte);
        int jq = j0q + rr;
        jq = jq < 0 ? 0 : (jq > 1023 ? 1023 : jq);
        gload_lds16(posq + ((long)jq << 6) + sel, (char*)PXq + c * 4096 + wbyte);
      }
#pragma unroll
      for (int c = 0; c < 2; c++) {
        const int u = c * 256 + tid;
        const int rr = u >> 3;
        const int sel = (((u & 7) ^ (rr & 7)) << 3);
        gload_lds16(kbase + ((long)(k0 + rr) << 6) + sel, (char*)Ks + c * 4096 + wbyte);
        gload_lds16(vbase + ((long)kt << 12) + ((long)rr << 6) + sel,
                    (char*)Vs + c * 4096 + wbyte);
      }
    }
    __syncthreads();

    // ---- phase B: c2p (10) + S (8) + p2c (10) MFMA cluster ------------------
    bf16x8 ka[2];
    ka[0] = lds_frag(Ks, wave * 16 + fr, fq);
    ka[1] = lds_frag(Ks, wave * 16 + fr, 4 + fq);
    __builtin_amdgcn_s_setprio(1);
    {
      f32x4 cw[5];
#pragma unroll
      for (int t = 0; t < 5; t++) cw[t] = f32x4{0.f, 0.f, 0.f, 0.f};
#pragma unroll
      for (int kc = 0; kc < 2; kc++)
#pragma unroll
        for (int t = 0; t < 5; t++) {
          const bf16x8 pb = lds_frag(PXk, wave * 16 + t * 16 + fr, kc * 4 + fq);
          cw[t] = __builtin_amdgcn_mfma_f32_16x16x32_bf16(qa[kc], pb, cw[t], 0, 0, 0);
        }
#pragma unroll
      for (int t = 0; t < 5; t++) {
        bf16x4 pk;
#pragma unroll
        for (int r = 0; r < 4; r++) pk[r] = (bf16)cw[t][r];
        *(bf16x4*)&c2p_w[(t * 16 + fr) * 20 + fq * 4] = pk;  // [t2][qi]
      }
    }
    f32x4 s[4];
#pragma unroll
    for (int n = 0; n < 4; n++) s[n] = f32x4{0.f, 0.f, 0.f, 0.f};
#pragma unroll
    for (int kc = 0; kc < 2; kc++)
#pragma unroll
      for (int n = 0; n < 4; n++) {
        const bf16x8 kb = lds_frag(Ks, n * 16 + fr, kc * 4 + fq);
        s[n] = __builtin_amdgcn_mfma_f32_16x16x32_bf16(qa[kc], kb, s[n], 0, 0, 0);
      }
    {
      f32x4 pw[5];
#pragma unroll
      for (int t = 0; t < 5; t++) pw[t] = f32x4{0.f, 0.f, 0.f, 0.f};
#pragma unroll
      for (int kc = 0; kc < 2; kc++)
#pragma unroll
        for (int t = 0; t < 5; t++) {
          const bf16x8 pb = lds_frag(PXq, (wave + t) * 16 + fr, kc * 4 + fq);
          pw[t] = __builtin_amdgcn_mfma_f32_16x16x32_bf16(ka[kc], pb, pw[t], 0, 0, 0);
        }
#pragma unroll
      for (int t = 0; t < 5; t++) {
        bf16x4 pk;
#pragma unroll
        for (int r = 0; r < 4; r++) pk[r] = (bf16)pw[t][r];
        *(bf16x4*)&p2c_T[((wave + t) * 16 + fr) * 68 + wave * 16 + fq * 4] = pk;
      }
    }
    __builtin_amdgcn_s_setprio(0);
    __syncthreads();

    // ---- phase D: gathers, defer-max softmax, p_l, PV ----------------------
    bf16x8 vb[2][4];
#pragma unroll
    for (int kc = 0; kc < 2; kc++)
#pragma unroll
      for (int n = 0; n < 4; n++) vb[kc][n] = lds_frag(Vs, n * 16 + fr, kc * 4 + fq);

    float st[4][4];
#pragma unroll
    for (int n = 0; n < 4; n++) {
      const int ki = n * 16 + fr;
      const float mb = (1.0f - mask[b * S_ + k0 + ki]) * (-1e9f * LOG2E_);
#pragma unroll
      for (int r = 0; r < 4; r++) {
        const int qi_s = fq * 4 + r;
        const float cv = (float)c2p_w[(qi_s - ki + 63) * 20 + qi_s];
        const float pv = (float)p2c_T[(ki - (wave * 16 + qi_s) + 63) * 68 + ki];
        st[n][r] = (s[n][r] + cv + pv) * SCL2_ + mb;  // log2 domain
      }
    }

    float pmax[4];
#pragma unroll
    for (int r = 0; r < 4; r++) {
      float v = fmaxf(fmaxf(st[0][r], st[1][r]), fmaxf(st[2][r], st[3][r]));
      pmax[r] = rowMax16(v);
    }
    const bool ok = (pmax[0] - m_r[0] <= THR2_) && (pmax[1] - m_r[1] <= THR2_) &&
                    (pmax[2] - m_r[2] <= THR2_) && (pmax[3] - m_r[3] <= THR2_);
    if (!__all(ok)) {
#pragma unroll
      for (int r = 0; r < 4; r++) {
        const float mn = fmaxf(m_r[r], pmax[r]);
        const float sc = exp2f(m_r[r] - mn);
        m_r[r] = mn;
        l_r[r] *= sc;
#pragma unroll
        for (int n = 0; n < 4; n++) o[n][r] *= sc;
      }
    }
    float rs[4] = {0.f, 0.f, 0.f, 0.f};
#pragma unroll
    for (int n = 0; n < 4; n++) {
      const int ki = n * 16 + fr;
#pragma unroll
      for (int r = 0; r < 4; r++) {
        const int qi_s = fq * 4 + r;
        const float p = exp2f(st[n][r] - m_r[r]);
        rs[r] += p;
        *(bf16*)(pl_base + qi_s * 128 + ((ki * 2) ^ ((qi_s & 7) << 4))) = (bf16)p;
      }
    }
#pragma unroll
    for (int r = 0; r < 4; r++) l_r[r] += rowSum16(rs[r]);

#pragma unroll
    for (int kc = 0; kc < 2; kc++) {
      const bf16x8 pa =
          *(const bf16x8*)(pl_base + fr * 128 + ((kc * 64 + fq * 16) ^ ((fr & 7) << 4)));
#pragma unroll
      for (int n = 0; n < 4; n++)
        o[n] = __builtin_amdgcn_mfma_f32_16x16x32_bf16(pa, vb[kc][n], o[n], 0, 0, 0);
    }
  }

  // ---- epilogue ----
#pragma unroll
  for (int r = 0; r < 4; r++) {
    const float inv = 1.f / l_r[r];
    const long row = (long)(b * S_ + q0 + wave * 16 + fq * 4 + r) * D_ + h * 64;
#pragma unroll
    for (int n = 0; n < 4; n++) ctx[row + n * 16 + fr] = (bf16)(o[n][r] * inv);
  }
}

// ------- weight transpose+convert, 4 square weights in one dispatch ---------
__global__ __launch_bounds__(256) void wtrans4(const float* __restrict__ Wq,
                                               const float* __restrict__ Wk,
                                               const float* __restrict__ Wv,
                                               const float* __restrict__ Wo,
                                               bf16* __restrict__ wqkvT,
                                               bf16* __restrict__ woT) {
  const int z = blockIdx.z;
  const int l = z >> 2, which = z & 3;
  const long DD = (long)D_ * D_;
  const float* W = (which == 0 ? Wq : which == 1 ? Wk : which == 2 ? Wv : Wo) + l * DD;
  bf16* WT = (which < 3) ? (wqkvT + (long)l * 3 * DD + which * DD) : (woT + (long)l * DD);
  __shared__ float t[32][33];
  const int n0 = blockIdx.x * 32, k0 = blockIdx.y * 32;
  const int tx = threadIdx.x & 31, ty = threadIdx.x >> 5;
#pragma unroll
  for (int i = ty; i < 32; i += 8) t[i][tx] = W[(long)(k0 + i) * D_ + n0 + tx];
  __syncthreads();
#pragma unroll
  for (int i = ty; i < 32; i += 8) WT[(long)(n0 + i) * D_ + k0 + tx] = (bf16)t[tx][i];
}

// ------- weight transpose+convert: W[K,N] f32 -> WT[N,K] bf16, z-batched ----
__global__ __launch_bounds__(256) void wtrans(const float* __restrict__ W,
                                              bf16* __restrict__ WT, int K, int N,
                                              long sW, long sT) {
  W += (long)blockIdx.z * sW;
  WT += (long)blockIdx.z * sT;
  __shared__ float t[32][33];
  const int n0 = blockIdx.x * 32, k0 = blockIdx.y * 32;
  const int tx = threadIdx.x & 31, ty = threadIdx.x >> 5;
#pragma unroll
  for (int i = ty; i < 32; i += 8) t[i][tx] = W[(long)(k0 + i) * N + n0 + tx];
  __syncthreads();
#pragma unroll
  for (int i = ty; i < 32; i += 8) WT[(long)(n0 + i) * K + k0 + tx] = (bf16)t[tx][i];
}

__global__ __launch_bounds__(256) void f2b(const float* __restrict__ in,
                                           bf16* __restrict__ out, long n) {
  long i = (long)blockIdx.x * 256 + threadIdx.x;
  if (i < n) out[i] = (bf16)in[i];
}

__global__ __launch_bounds__(256) void bias_concat(const float* __restrict__ bq,
                                                   const float* __restrict__ bk,
                                                   const float* __restrict__ bv,
                                                   float* __restrict__ bqkv) {
  const int i = blockIdx.x * 256 + threadIdx.x;
  const int l = i / (3 * D_), s = (i % (3 * D_)) / D_, d = i % D_;
  const float* src = s == 0 ? bq : (s == 1 ? bk : bv);
  bqkv[i] = src[l * D_ + d];
}

// ---------------- embedding + LN + mask (f32x4 vectorized) ------------------
__global__ __launch_bounds__(256) void embed_ln(
    const int* __restrict__ ids, const int* __restrict__ segs,
    const float* __restrict__ mask, const float* __restrict__ tok,
    const float* __restrict__ seg, const float* __restrict__ g,
    const float* __restrict__ bta, float* __restrict__ h, bf16* __restrict__ hb) {
  __shared__ float r1[4], r2[4];
  const int t = blockIdx.x;
  const int d4 = threadIdx.x;
  const long tb4 = (long)ids[t] * 256;
  const long sb4 = (long)segs[t] * 256;
  const long b4 = (long)t * 256;
  f32x4 x = ((const f32x4*)tok)[tb4 + d4];
  const f32x4 sv = ((const f32x4*)seg)[sb4 + d4];
#pragma unroll
  for (int r = 0; r < 4; r++) x[r] += sv[r];
  float sm = x[0] + x[1] + x[2] + x[3];
  sm = blockSum4(sm, r1);
  const float mean = sm * (1.f / D_);
  float vs = 0.f;
#pragma unroll
  for (int r = 0; r < 4; r++) {
    const float c = x[r] - mean;
    vs += c * c;
  }
  vs = blockSum4(vs, r2);
  const float rstd = rsqrtf(vs * (1.f / D_) + 1e-12f);
  const float mk = mask[t];
  const f32x4 gv = ((const f32x4*)g)[d4];
  const f32x4 bv = ((const f32x4*)bta)[d4];
  f32x4 y;
  bf16x4 yb;
#pragma unroll
  for (int r = 0; r < 4; r++) {
    y[r] = ((x[r] - mean) * rstd * gv[r] + bv[r]) * mk;
    yb[r] = (bf16)y[r];
  }
  ((f32x4*)h)[b4 + d4] = y;
  *(bf16x4*)&hb[(b4 + d4) * 4] = yb;
}

// --- residual + bf16 split-K reduce + bias + LN (fused, vectorized) ---------
template <int P>
__global__ __launch_bounds__(256) void ln_residual_red(
    const float* __restrict__ hin, float* __restrict__ hout,
    const bf16* __restrict__ part, long pstride4,
    const float* __restrict__ bias, const float* __restrict__ g,
    const float* __restrict__ bta, bf16* __restrict__ hb) {
  __shared__ float r1[4], r2[4];
  const int d4 = threadIdx.x;
  const long b4 = (long)blockIdx.x * 256;
  f32x4 x = ((const f32x4*)hin)[b4 + d4];
  const f32x4 bi = ((const f32x4*)bias)[d4];
#pragma unroll
  for (int r = 0; r < 4; r++) x[r] += bi[r];
#pragma unroll
  for (int z = 0; z < P; z++) {
    const bf16x4 pv = ((const bf16x4*)part)[(long)z * pstride4 + b4 + d4];
#pragma unroll
    for (int r = 0; r < 4; r++) x[r] += (float)pv[r];
  }
  float sm = x[0] + x[1] + x[2] + x[3];
  sm = blockSum4(sm, r1);
  const float mean = sm * (1.f / D_);
  float vs = 0.f;
#pragma unroll
  for (int r = 0; r < 4; r++) {
    const float c = x[r] - mean;
    vs += c * c;
  }
  vs = blockSum4(vs, r2);
  const float rstd = rsqrtf(vs * (1.f / D_) + 1e-12f);
  const f32x4 gv = ((const f32x4*)g)[d4];
  const f32x4 bv = ((const f32x4*)bta)[d4];
  f32x4 y;
  bf16x4 yb;
#pragma unroll
  for (int r = 0; r < 4; r++) {
    y[r] = (x[r] - mean) * rstd * gv[r] + bv[r];
    yb[r] = (bf16)y[r];
  }
  ((f32x4*)hout)[b4 + d4] = y;
  *(bf16x4*)&hb[(b4 + d4) * 4] = yb;
}

// ============================================================================
extern "C" void kernel_launch(void* const* d_in, const int* in_sizes, int n_in,
                              void* d_out, int out_size, void* d_ws, size_t ws_size,
                              hipStream_t stream) {
  (void)in_sizes; (void)n_in; (void)out_size; (void)ws_size;
  const int* input_ids = (const int*)d_in[0];
  const int* segment_ids = (const int*)d_in[1];
  const float* attention_mask = (const float*)d_in[2];
  const float* tok_emb = (const float*)d_in[3];
  const float* seg_emb = (const float*)d_in[4];
  const float* emb_ln_g = (const float*)d_in[5];
  const float* emb_ln_b = (const float*)d_in[6];
  const float* rel_emb = (const float*)d_in[7];
  const float* Wq = (const float*)d_in[8];
  const float* bq = (const float*)d_in[9];
  const float* Wk = (const float*)d_in[10];
  const float* bk = (const float*)d_in[11];
  const float* Wv = (const float*)d_in[12];
  const float* bv = (const float*)d_in[13];
  const float* Wo = (const float*)d_in[14];
  const float* bo = (const float*)d_in[15];
  const float* ln1_g = (const float*)d_in[16];
  const float* ln1_b = (const float*)d_in[17];
  const float* W1 = (const float*)d_in[18];
  const float* b1 = (const float*)d_in[19];
  const float* W2 = (const float*)d_in[20];
  const float* b2 = (const float*)d_in[21];
  const float* ln2_g = (const float*)d_in[22];
  const float* ln2_b = (const float*)d_in[23];

  const long DD = (long)D_ * D_;
  const long DF = (long)D_ * F_;
  const int D3 = 3 * D_;

  char* ws = (char*)d_ws;
  auto alloc = [&](size_t bytes) {
    char* p = ws;
    ws += (bytes + 255) & ~(size_t)255;
    return p;
  };
  bf16* wqkvT = (bf16*)alloc((size_t)L_ * 3 * DD * 2);
  bf16* woT = (bf16*)alloc((size_t)L_ * DD * 2);
  bf16* w1T = (bf16*)alloc((size_t)L_ * DF * 2);
  bf16* w2T = (bf16*)alloc((size_t)L_ * DF * 2);
  float* bqkv = (float*)alloc((size_t)L_ * 3 * D_ * 4);
  bf16* relb = (bf16*)alloc((size_t)2 * SPAN_ * D_ * 2);
  float* hbuf = (float*)alloc((size_t)B_ * S_ * D_ * 4);
  bf16* hb = (bf16*)alloc((size_t)B_ * S_ * D_ * 2);
  bf16* qkv = (bf16*)alloc((size_t)B_ * S_ * 3 * D_ * 2);
  bf16* kp = (bf16*)alloc((size_t)B_ * H_ * S_ * DH_ * 2);
  bf16* vp = (bf16*)alloc((size_t)B_ * H_ * S_ * DH_ * 2);
  bf16* pospk = (bf16*)alloc((size_t)L_ * POSL_ * 2);
  bf16* ctxb = (bf16*)alloc((size_t)B_ * S_ * D_ * 2);
  bf16* ff1b = (bf16*)alloc((size_t)B_ * S_ * F_ * 2);
  bf16* kpart = (bf16*)alloc((size_t)4 * B_ * S_ * D_ * 2);  // bf16 partials
  const long PSTR = (long)B_ * S_ * D_;

  // ---- one-time per call ----
  wtrans4<<<dim3(D_ / 32, D_ / 32, 4 * L_), 256, 0, stream>>>(Wq, Wk, Wv, Wo, wqkvT, woT);
  wtrans<<<dim3(F_ / 32, D_ / 32, L_), 256, 0, stream>>>(W1, w1T, D_, F_, DF, DF);
  wtrans<<<dim3(D_ / 32, F_ / 32, L_), 256, 0, stream>>>(W2, w2T, F_, D_, DF, DF);
  bias_concat<<<dim3(L_ * 3 * D_ / 256), 256, 0, stream>>>(bq, bk, bv, bqkv);
  f2b<<<dim3((2 * SPAN_ * D_) / 256), 256, 0, stream>>>(rel_emb, relb, (long)2 * SPAN_ * D_);
  gemm_bt<5><<<dim3((2 * D_) / 128, (2 * SPAN_) / 128, L_), 256, 0, stream>>>(
      relb, wqkvT, bqkv, pospk, 2 * SPAN_, 2 * D_, D_, D_, D_, 0, 1.f,
      0, 3 * DD, POSL_, 3 * D_);
  embed_ln<<<dim3(B_ * S_), 256, 0, stream>>>(input_ids, segment_ids, attention_mask,
                                              tok_emb, seg_emb, emb_ln_g, emb_ln_b, hbuf, hb);

  const size_t SH = 131072;  // 128 KiB dynamic LDS for gemm256

  for (int l = 0; l < L_; ++l) {
    const bf16* wqkv_ = wqkvT + (long)l * 3 * DD;
    const bf16* wo_ = woT + (long)l * DD;
    const bf16* w1_ = w1T + (long)l * DF;
    const bf16* w2_ = w2T + (long)l * DF;
    const float* bqkv_ = bqkv + (long)l * 3 * D_;
    const float* bo_ = bo + (long)l * D_;
    const float* b1_ = b1 + (long)l * F_;
    const float* b2_ = b2 + (long)l * D_;

    // fused q,k,v projection: qkv[B*S, 3D]  (128-tile, 768 blocks = 3/CU)
    gemm_bt<3><<<dim3(D3 / 128, (B_ * S_) / 128, 1), 256, 0, stream>>>(
        hb, wqkv_, bqkv_, qkv, B_ * S_, D3, D_, D_, D_, D3, 1.f, 0, 0, 0, 0);
    repack_kv<<<dim3(16, B_ * H_), 256, 0, stream>>>(qkv, kp, vp);

    // fused attention (3-barrier structure, r14-proven)
    attn_fused<<<dim3(1024), 256, 0, stream>>>(qkv, kp, vp, pospk + (long)l * POSL_,
                                               attention_mask, ctxb);

    // attention output projection: split-K2 128-tile, bf16 partials
    gemm_bt<6><<<dim3(D_ / 128, (B_ * S_) / 128, 2), 256, 0, stream>>>(
        ctxb, wo_, nullptr, kpart, B_ * S_, D_, D_ / 2, D_, D_, D_, 1.f,
        D_ / 2, D_ / 2, PSTR, 0);
    ln_residual_red<2><<<dim3(B_ * S_), 256, 0, stream>>>(
        hbuf, hbuf, kpart, PSTR / 4, bo_, ln1_g + l * D_, ln1_b + l * D_, hb);

    // FFN
    gemm256<4><<<dim3(F_ / 256, (B_ * S_) / 256, 1), 512, SH, stream>>>(
        hb, w1_, b1_, ff1b, D_, D_, D_, F_, 0, 0, 0);
    gemm256<6><<<dim3(D_ / 256, (B_ * S_) / 256, 4), 512, SH, stream>>>(
        ff1b, w2_, nullptr, kpart, F_ / 4, F_, F_, D_, F_ / 4, F_ / 4, PSTR);
    float* hout = (l == L_ - 1) ? (float*)d_out : hbuf;
    ln_residual_red<4><<<dim3(B_ * S_), 256, 0, stream>>>(
        hbuf, hout, kpart, PSTR / 4, b2_, ln2_g + l * D_, ln2_b + l * D_, hb);
  }
}